// Round 5
// baseline (301.747 us; speedup 1.0000x reference)
//
#include <hip/hip_runtime.h>
#include <hip/hip_bf16.h>
#include <stdint.h>

#define T_TOK 4096
#define NEXP  8
#define HDIM  1024
#define IDIM  2048
#define TOPK  2

typedef __attribute__((ext_vector_type(8))) short short8;
typedef __attribute__((ext_vector_type(4))) float f32x4;

__device__ __forceinline__ unsigned short f2bf(float f) {
    union { float f; unsigned int u; } v; v.f = f;
    unsigned int u = v.u;
    return (unsigned short)((u + 0x7fffu + ((u >> 16) & 1u)) >> 16);
}
__device__ __forceinline__ float bf2f(unsigned short s) {
    union { unsigned int u; float f; } v; v.u = ((unsigned int)s) << 16;
    return v.f;
}
__device__ __forceinline__ void gload_lds16(const void* g, void* l) {
    __builtin_amdgcn_global_load_lds(
        (const __attribute__((address_space(1))) unsigned int*)g,
        (__attribute__((address_space(3))) unsigned int*)l,
        16, 0, 0);
}
#define MFMA16(A, B, C) __builtin_amdgcn_mfma_f32_16x16x32_bf16(A, B, C, 0, 0, 0)

// ---------------- routing ----------------

__global__ void init_k(int* cnt) {
    if (threadIdx.x < NEXP) cnt[threadIdx.x] = 0;
}

__global__ void router_k(const float* __restrict__ logits, int* __restrict__ cnt,
                         int* __restrict__ eids, float* __restrict__ ews) {
    int t = blockIdx.x * blockDim.x + threadIdx.x;
    if (t >= T_TOK) return;
    const float4* lp = (const float4*)(logits + (size_t)t * NEXP);
    float4 a = lp[0], b = lp[1];
    float l[NEXP] = {a.x, a.y, a.z, a.w, b.x, b.y, b.z, b.w};
    int e0 = 0; float b0 = l[0];
    #pragma unroll
    for (int e = 1; e < NEXP; ++e) if (l[e] > b0) { b0 = l[e]; e0 = e; }
    int e1 = -1; float b1 = -1e30f;
    #pragma unroll
    for (int e = 0; e < NEXP; ++e) { if (e == e0) continue; if (l[e] > b1) { b1 = l[e]; e1 = e; } }
    float tt = __expf(b1 - b0);
    float w0 = 1.0f / (1.0f + tt);
    float w1 = 1.0f - w0;
    eids[2 * t] = e0; eids[2 * t + 1] = e1;
    ews[2 * t] = w0;  ews[2 * t + 1] = w1;
    atomicAdd(&cnt[e0], 1); atomicAdd(&cnt[e1], 1);
}

// builds offsets + (e, mt) work list for BM=256 GEMM blocks
__global__ void offs_k(const int* __restrict__ cnt, int* __restrict__ offs,
                       int* __restrict__ cursor, int* __restrict__ work) {
    if (threadIdx.x == 0) {
        int s = 0, n = 0;
        for (int e = 0; e < NEXP; ++e) {
            offs[e] = s; cursor[e] = s;
            int nm = (cnt[e] + 255) >> 8;
            for (int m = 0; m < nm; ++m) work[1 + n++] = (e << 8) | m;
            s += cnt[e];
        }
        offs[NEXP] = s;
        work[0] = n;
    }
}

__global__ void scatter_k(const int* __restrict__ eids, const float* __restrict__ ews,
                          int* __restrict__ cursor, int* __restrict__ tokid,
                          float* __restrict__ tokw, int* __restrict__ pos) {
    int t = blockIdx.x * blockDim.x + threadIdx.x;
    if (t >= T_TOK) return;
    #pragma unroll
    for (int k = 0; k < TOPK; ++k) {
        int e = eids[2 * t + k];
        int p = atomicAdd(&cursor[e], 1);
        tokid[p] = t; tokw[p] = ews[2 * t + k]; pos[2 * t + k] = p;
    }
}

// ---------------- fp32 -> bf16 convert ----------------

__global__ void cvt_all_k(const float* __restrict__ x, const float* __restrict__ w13,
                          const float* __restrict__ w2, unsigned short* __restrict__ xb,
                          unsigned short* __restrict__ w13b, unsigned short* __restrict__ w2b) {
    const int n0 = T_TOK * HDIM / 8;
    const int n1 = NEXP * 2 * IDIM * HDIM / 8;
    const int n2 = NEXP * HDIM * IDIM / 8;
    const int total = n0 + n1 + n2;
    for (int i = blockIdx.x * blockDim.x + threadIdx.x; i < total; i += gridDim.x * blockDim.x) {
        const float* s; unsigned short* d; int j;
        if (i < n0) { s = x; d = xb; j = i; }
        else if (i < n0 + n1) { s = w13; d = w13b; j = i - n0; }
        else { s = w2; d = w2b; j = i - n0 - n1; }
        const float4* p = (const float4*)(s + (size_t)j * 8);
        float4 a = p[0], b = p[1];
        union { unsigned short us[8]; short8 v; } r;
        r.us[0] = f2bf(a.x); r.us[1] = f2bf(a.y); r.us[2] = f2bf(a.z); r.us[3] = f2bf(a.w);
        r.us[4] = f2bf(b.x); r.us[5] = f2bf(b.y); r.us[6] = f2bf(b.z); r.us[7] = f2bf(b.w);
        *(short8*)(d + (size_t)j * 8) = r.v;
    }
}

// ---------------- GEMM1: h = silu(x@W1^T) * (x@W3^T) ----------------
// m201 geometry: BM=256 tokens x 256 B-rows (128 gate + 128 up interleaved
// in 32-row groups per wn), BK=64, 8 waves (2M x 4N), per-wave 128x64.
// LDS: 2 slots x [A:2kh x 256x32 | B:2kh x 256x32] = 128KB. Half-tile (K-half)
// staging, one half per phase, vmcnt(4) twice per K-tile (never drains).
// grid (IDIM/128=16, 40, 1) with work-list.

#define G1SLOT 32768   // ushorts per K-tile slot

__global__ __launch_bounds__(512, 1) void gemm1_k(
    const unsigned short* __restrict__ xb, const unsigned short* __restrict__ w13b,
    const int* __restrict__ tokid, const int* __restrict__ offs,
    const int* __restrict__ work, unsigned short* __restrict__ hbuf)
{
    extern __shared__ unsigned short lds[];
    const int nw = work[0];
    if ((int)blockIdx.y >= nw) return;
    const int wk = work[1 + blockIdx.y];
    const int e = wk >> 8, mt = wk & 255;
    const int off_e = offs[e];
    const int cnt_e = offs[e + 1] - off_e;
    const int nt = blockIdx.x;

    const int tid = threadIdx.x;
    const int w = tid >> 6, lane = tid & 63;
    const int ln15 = lane & 15, l16 = lane >> 4;
    const int wm = w >> 2, wn = w & 3;

    // staging pointers: per K-half (kh), per round (j): 512-thread x 16B
    const char* srcA[2][2]; int dstA[2][2];
    const char* srcB[2][2]; int dstB[2][2];
    #pragma unroll
    for (int kh = 0; kh < 2; ++kh) {
        #pragma unroll
        for (int j = 0; j < 2; ++j) {
            int S = j * 512 + tid;
            int row = S >> 2, rs = S & 3;
            int g = rs ^ ((row >> 1) & 3);            // inverse of read swizzle
            int tr = mt * 256 + row; if (tr >= cnt_e) tr = cnt_e - 1;
            srcA[kh][j] = (const char*)(xb + (size_t)tokid[off_e + tr] * HDIM + kh * 32 + g * 8);
            dstA[kh][j] = kh * 8192 + S * 8;
            int wg = row >> 6, q = (row >> 5) & 1, sub = row & 31;
            int grow = q * IDIM + nt * 128 + wg * 32 + sub;
            srcB[kh][j] = (const char*)(w13b + (size_t)e * (2 * IDIM * HDIM) + (size_t)grow * HDIM + kh * 32 + g * 8);
            dstB[kh][j] = 16384 + kh * 8192 + S * 8;
        }
    }

    const f32x4 z4 = {0.f, 0.f, 0.f, 0.f};
    f32x4 acc[8][4];
    #pragma unroll
    for (int m = 0; m < 8; ++m)
        #pragma unroll
        for (int n = 0; n < 4; ++n) acc[m][n] = z4;

    const int axor = (ln15 >> 1) & 3;
    const int sl = (l16 ^ axor) * 8;
    const int aoff = (wm * 128 + ln15) * 32 + sl;            // + kh*8192 + m*512
    const int boff = 16384 + (wn * 64 + ln15) * 32 + sl;     // + kh*8192 + n*512

    // prologue: stage tile 0 (k0 halves first, then k1)
    gload_lds16(srcA[0][0], lds + dstA[0][0]);
    gload_lds16(srcA[0][1], lds + dstA[0][1]);
    gload_lds16(srcB[0][0], lds + dstB[0][0]);
    gload_lds16(srcB[0][1], lds + dstB[0][1]);
    gload_lds16(srcA[1][0], lds + dstA[1][0]);
    gload_lds16(srcA[1][1], lds + dstA[1][1]);
    gload_lds16(srcB[1][0], lds + dstB[1][0]);
    gload_lds16(srcB[1][1], lds + dstB[1][1]);
    asm volatile("s_waitcnt vmcnt(4)" ::: "memory");
    __builtin_amdgcn_s_barrier();

    const int KT = HDIM / 64;   // 16
    short8 a[8], b[4];
    for (int kt = 0; kt < KT - 1; ++kt) {
        const unsigned short* buf = lds + (kt & 1) * G1SLOT;
        unsigned short* sb = lds + ((kt + 1) & 1) * G1SLOT;
        const int ko = (kt + 1) * 128;   // bytes

        // ---- P0: kk0, frags a(all m), b(n0,n1); stage A-k0(kt+1)
        #pragma unroll
        for (int m = 0; m < 8; ++m) a[m] = *(const short8*)&buf[aoff + m * 512];
        b[0] = *(const short8*)&buf[boff];
        b[1] = *(const short8*)&buf[boff + 512];
        gload_lds16(srcA[0][0] + ko, sb + dstA[0][0]);
        gload_lds16(srcA[0][1] + ko, sb + dstA[0][1]);
        __builtin_amdgcn_s_barrier();
        __builtin_amdgcn_s_setprio(1);
        #pragma unroll
        for (int m = 0; m < 8; ++m) {
            acc[m][0] = MFMA16(a[m], b[0], acc[m][0]);
            acc[m][1] = MFMA16(a[m], b[1], acc[m][1]);
        }
        __builtin_amdgcn_s_setprio(0);
        __builtin_amdgcn_s_barrier();

        // ---- P1: kk0, b(n2,n3); stage B-k0(kt+1); W1 guards this tile's k1
        b[2] = *(const short8*)&buf[boff + 1024];
        b[3] = *(const short8*)&buf[boff + 1536];
        gload_lds16(srcB[0][0] + ko, sb + dstB[0][0]);
        gload_lds16(srcB[0][1] + ko, sb + dstB[0][1]);
        __builtin_amdgcn_s_barrier();
        __builtin_amdgcn_s_setprio(1);
        #pragma unroll
        for (int m = 0; m < 8; ++m) {
            acc[m][2] = MFMA16(a[m], b[2], acc[m][2]);
            acc[m][3] = MFMA16(a[m], b[3], acc[m][3]);
        }
        __builtin_amdgcn_s_setprio(0);
        asm volatile("s_waitcnt vmcnt(4)" ::: "memory");
        __builtin_amdgcn_s_barrier();

        // ---- P2: kk1, frags; stage A-k1(kt+1)
        #pragma unroll
        for (int m = 0; m < 8; ++m) a[m] = *(const short8*)&buf[8192 + aoff + m * 512];
        b[0] = *(const short8*)&buf[8192 + boff];
        b[1] = *(const short8*)&buf[8192 + boff + 512];
        gload_lds16(srcA[1][0] + ko, sb + dstA[1][0]);
        gload_lds16(srcA[1][1] + ko, sb + dstA[1][1]);
        __builtin_amdgcn_s_barrier();
        __builtin_amdgcn_s_setprio(1);
        #pragma unroll
        for (int m = 0; m < 8; ++m) {
            acc[m][0] = MFMA16(a[m], b[0], acc[m][0]);
            acc[m][1] = MFMA16(a[m], b[1], acc[m][1]);
        }
        __builtin_amdgcn_s_setprio(0);
        __builtin_amdgcn_s_barrier();

        // ---- P3: kk1, b(n2,n3); stage B-k1(kt+1); W2 guards kt+1's k0
        b[2] = *(const short8*)&buf[8192 + boff + 1024];
        b[3] = *(const short8*)&buf[8192 + boff + 1536];
        gload_lds16(srcB[1][0] + ko, sb + dstB[1][0]);
        gload_lds16(srcB[1][1] + ko, sb + dstB[1][1]);
        __builtin_amdgcn_s_barrier();
        __builtin_amdgcn_s_setprio(1);
        #pragma unroll
        for (int m = 0; m < 8; ++m) {
            acc[m][2] = MFMA16(a[m], b[2], acc[m][2]);
            acc[m][3] = MFMA16(a[m], b[3], acc[m][3]);
        }
        __builtin_amdgcn_s_setprio(0);
        asm volatile("s_waitcnt vmcnt(4)" ::: "memory");
        __builtin_amdgcn_s_barrier();
    }

    // ---- peeled last tile (no staging; full drain before kk1 reads)
    {
        const unsigned short* buf = lds + ((KT - 1) & 1) * G1SLOT;
        #pragma unroll
        for (int m = 0; m < 8; ++m) a[m] = *(const short8*)&buf[aoff + m * 512];
        #pragma unroll
        for (int n = 0; n < 4; ++n) b[n] = *(const short8*)&buf[boff + n * 512];
        __builtin_amdgcn_s_barrier();
        __builtin_amdgcn_s_setprio(1);
        #pragma unroll
        for (int m = 0; m < 8; ++m)
            #pragma unroll
            for (int n = 0; n < 4; ++n)
                acc[m][n] = MFMA16(a[m], b[n], acc[m][n]);
        __builtin_amdgcn_s_setprio(0);
        asm volatile("s_waitcnt vmcnt(0)" ::: "memory");
        __builtin_amdgcn_s_barrier();
        #pragma unroll
        for (int m = 0; m < 8; ++m) a[m] = *(const short8*)&buf[8192 + aoff + m * 512];
        #pragma unroll
        for (int n = 0; n < 4; ++n) b[n] = *(const short8*)&buf[8192 + boff + n * 512];
        __builtin_amdgcn_s_setprio(1);
        #pragma unroll
        for (int m = 0; m < 8; ++m)
            #pragma unroll
            for (int n = 0; n < 4; ++n)
                acc[m][n] = MFMA16(a[m], b[n], acc[m][n]);
        __builtin_amdgcn_s_setprio(0);
    }

    // epilogue: silu(gate)*up -> bf16; n-frags 0,1 = gate, 2,3 = up (same cols)
    #pragma unroll
    for (int m = 0; m < 8; ++m) {
        #pragma unroll
        for (int i = 0; i < 4; ++i) {
            int r = mt * 256 + wm * 128 + m * 16 + l16 * 4 + i;
            if (r >= cnt_e) continue;
            size_t rb = (size_t)(off_e + r) * IDIM;
            #pragma unroll
            for (int nn = 0; nn < 2; ++nn) {
                int col = nt * 128 + wn * 32 + nn * 16 + ln15;
                float gv = acc[m][nn][i], uv = acc[m][2 + nn][i];
                float hv = gv / (1.f + __expf(-gv)) * uv;
                hbuf[rb + col] = f2bf(hv);
            }
        }
    }
}

// ---------------- GEMM2: pb = bf16( tokw * (h @ W2^T) ) ----------------
// BM=256, BN=128, BK=64, 8 waves (4M x 2N), per-wave 64x64.
// LDS: 2 slots x [A:2kh x 256x32 | B:2kh x 128x32] = 96KB. 2 phases/K-tile,
// half-tile staging (3 loads/phase), vmcnt(3) twice per tile.
// grid (HDIM/128=8, 40, 1) with work-list.

#define G2SLOT 24576

__global__ __launch_bounds__(512, 1) void gemm2_k(
    const unsigned short* __restrict__ hbuf, const unsigned short* __restrict__ w2b,
    const int* __restrict__ offs, const int* __restrict__ work,
    const float* __restrict__ tokw, unsigned short* __restrict__ pb)
{
    extern __shared__ unsigned short lds[];
    const int nw = work[0];
    if ((int)blockIdx.y >= nw) return;
    const int wk = work[1 + blockIdx.y];
    const int e = wk >> 8, mt = wk & 255;
    const int off_e = offs[e];
    const int cnt_e = offs[e + 1] - off_e;
    const int nt = blockIdx.x;

    const int tid = threadIdx.x;
    const int w = tid >> 6, lane = tid & 63;
    const int ln15 = lane & 15, l16 = lane >> 4;
    const int wm = w >> 1, wn = w & 1;

    const char* srcA[2][2]; int dstA[2][2];
    const char* srcB[2];    int dstB[2];
    #pragma unroll
    for (int kh = 0; kh < 2; ++kh) {
        #pragma unroll
        for (int j = 0; j < 2; ++j) {
            int S = j * 512 + tid;
            int row = S >> 2, rs = S & 3;
            int g = rs ^ ((row >> 1) & 3);
            int tr = mt * 256 + row; if (tr >= cnt_e) tr = cnt_e - 1;
            srcA[kh][j] = (const char*)(hbuf + (size_t)(off_e + tr) * IDIM + kh * 32 + g * 8);
            dstA[kh][j] = kh * 8192 + S * 8;
        }
        int S = tid;
        int row = S >> 2, rs = S & 3;
        int g = rs ^ ((row >> 1) & 3);
        srcB[kh] = (const char*)(w2b + (size_t)e * (HDIM * IDIM) + (size_t)(nt * 128 + row) * IDIM + kh * 32 + g * 8);
        dstB[kh] = 16384 + kh * 4096 + S * 8;
    }

    const f32x4 z4 = {0.f, 0.f, 0.f, 0.f};
    f32x4 acc[4][4];
    #pragma unroll
    for (int m = 0; m < 4; ++m)
        #pragma unroll
        for (int n = 0; n < 4; ++n) acc[m][n] = z4;

    const int axor = (ln15 >> 1) & 3;
    const int sl = (l16 ^ axor) * 8;
    const int aoff = (wm * 64 + ln15) * 32 + sl;             // + kh*8192 + m*512
    const int boff = 16384 + (wn * 64 + ln15) * 32 + sl;     // + kh*4096 + n*512

    // prologue: k0 halves first (3 loads), then k1
    gload_lds16(srcA[0][0], lds + dstA[0][0]);
    gload_lds16(srcA[0][1], lds + dstA[0][1]);
    gload_lds16(srcB[0],    lds + dstB[0]);
    gload_lds16(srcA[1][0], lds + dstA[1][0]);
    gload_lds16(srcA[1][1], lds + dstA[1][1]);
    gload_lds16(srcB[1],    lds + dstB[1]);
    asm volatile("s_waitcnt vmcnt(3)" ::: "memory");
    __builtin_amdgcn_s_barrier();

    const int KT = IDIM / 64;   // 32
    short8 a[4], b[4];
    for (int kt = 0; kt < KT - 1; ++kt) {
        const unsigned short* buf = lds + (kt & 1) * G2SLOT;
        unsigned short* sb = lds + ((kt + 1) & 1) * G2SLOT;
        const int ko = (kt + 1) * 128;

        // ---- P0: kk0; stage k0(kt+1); W guards this tile's k1
        #pragma unroll
        for (int m = 0; m < 4; ++m) a[m] = *(const short8*)&buf[aoff + m * 512];
        #pragma unroll
        for (int n = 0; n < 4; ++n) b[n] = *(const short8*)&buf[boff + n * 512];
        gload_lds16(srcA[0][0] + ko, sb + dstA[0][0]);
        gload_lds16(srcA[0][1] + ko, sb + dstA[0][1]);
        gload_lds16(srcB[0] + ko,    sb + dstB[0]);
        __builtin_amdgcn_s_barrier();
        __builtin_amdgcn_s_setprio(1);
        #pragma unroll
        for (int m = 0; m < 4; ++m)
            #pragma unroll
            for (int n = 0; n < 4; ++n)
                acc[m][n] = MFMA16(a[m], b[n], acc[m][n]);
        __builtin_amdgcn_s_setprio(0);
        asm volatile("s_waitcnt vmcnt(3)" ::: "memory");
        __builtin_amdgcn_s_barrier();

        // ---- P1: kk1; stage k1(kt+1); W guards kt+1's k0
        #pragma unroll
        for (int m = 0; m < 4; ++m) a[m] = *(const short8*)&buf[8192 + aoff + m * 512];
        #pragma unroll
        for (int n = 0; n < 4; ++n) b[n] = *(const short8*)&buf[4096 + boff + n * 512];
        gload_lds16(srcA[1][0] + ko, sb + dstA[1][0]);
        gload_lds16(srcA[1][1] + ko, sb + dstA[1][1]);
        gload_lds16(srcB[1] + ko,    sb + dstB[1]);
        __builtin_amdgcn_s_barrier();
        __builtin_amdgcn_s_setprio(1);
        #pragma unroll
        for (int m = 0; m < 4; ++m)
            #pragma unroll
            for (int n = 0; n < 4; ++n)
                acc[m][n] = MFMA16(a[m], b[n], acc[m][n]);
        __builtin_amdgcn_s_setprio(0);
        asm volatile("s_waitcnt vmcnt(3)" ::: "memory");
        __builtin_amdgcn_s_barrier();
    }
    // ---- peeled last tile
    {
        const unsigned short* buf = lds + ((KT - 1) & 1) * G2SLOT;
        #pragma unroll
        for (int m = 0; m < 4; ++m) a[m] = *(const short8*)&buf[aoff + m * 512];
        #pragma unroll
        for (int n = 0; n < 4; ++n) b[n] = *(const short8*)&buf[boff + n * 512];
        __builtin_amdgcn_s_barrier();
        __builtin_amdgcn_s_setprio(1);
        #pragma unroll
        for (int m = 0; m < 4; ++m)
            #pragma unroll
            for (int n = 0; n < 4; ++n)
                acc[m][n] = MFMA16(a[m], b[n], acc[m][n]);
        __builtin_amdgcn_s_setprio(0);
        asm volatile("s_waitcnt vmcnt(0)" ::: "memory");
        __builtin_amdgcn_s_barrier();
        #pragma unroll
        for (int m = 0; m < 4; ++m) a[m] = *(const short8*)&buf[8192 + aoff + m * 512];
        #pragma unroll
        for (int n = 0; n < 4; ++n) b[n] = *(const short8*)&buf[4096 + boff + n * 512];
        __builtin_amdgcn_s_setprio(1);
        #pragma unroll
        for (int m = 0; m < 4; ++m)
            #pragma unroll
            for (int n = 0; n < 4; ++n)
                acc[m][n] = MFMA16(a[m], b[n], acc[m][n]);
        __builtin_amdgcn_s_setprio(0);
    }

    #pragma unroll
    for (int m = 0; m < 4; ++m) {
        #pragma unroll
        for (int i = 0; i < 4; ++i) {
            int r = mt * 256 + wm * 64 + m * 16 + l16 * 4 + i;
            if (r >= cnt_e) continue;
            float wgt = tokw[off_e + r];
            size_t rb = (size_t)(off_e + r) * HDIM;
            #pragma unroll
            for (int n = 0; n < 4; ++n) {
                int col = nt * 128 + wn * 64 + n * 16 + ln15;
                pb[rb + col] = f2bf(wgt * acc[m][n][i]);
            }
        }
    }
}

// ---------------- combine ----------------

__global__ void combine2_k(const unsigned short* __restrict__ pb, const int* __restrict__ pos,
                           float* __restrict__ out) {
    int idx = blockIdx.x * blockDim.x + threadIdx.x;   // T*H/8 threads
    int t = idx >> 7, c8 = idx & 127;
    int p0 = pos[2 * t], p1 = pos[2 * t + 1];
    short8 a = *(const short8*)(pb + (size_t)p0 * HDIM + c8 * 8);
    short8 b = *(const short8*)(pb + (size_t)p1 * HDIM + c8 * 8);
    float4 o0, o1;
    o0.x = bf2f((unsigned short)a[0]) + bf2f((unsigned short)b[0]);
    o0.y = bf2f((unsigned short)a[1]) + bf2f((unsigned short)b[1]);
    o0.z = bf2f((unsigned short)a[2]) + bf2f((unsigned short)b[2]);
    o0.w = bf2f((unsigned short)a[3]) + bf2f((unsigned short)b[3]);
    o1.x = bf2f((unsigned short)a[4]) + bf2f((unsigned short)b[4]);
    o1.y = bf2f((unsigned short)a[5]) + bf2f((unsigned short)b[5]);
    o1.z = bf2f((unsigned short)a[6]) + bf2f((unsigned short)b[6]);
    o1.w = bf2f((unsigned short)a[7]) + bf2f((unsigned short)b[7]);
    float* op = out + (size_t)t * HDIM + c8 * 8;
    ((float4*)op)[0] = o0;
    ((float4*)op)[1] = o1;
}

// ---------------- launch ----------------

extern "C" void kernel_launch(void* const* d_in, const int* in_sizes, int n_in,
                              void* d_out, int out_size, void* d_ws, size_t ws_size,
                              hipStream_t stream) {
    const float* x      = (const float*)d_in[0];
    const float* logits = (const float*)d_in[1];
    const float* w13    = (const float*)d_in[2];
    const float* w2     = (const float*)d_in[3];
    float* out = (float*)d_out;

    char* ws = (char*)d_ws;
    size_t off = 0;
    auto carve = [&](size_t bytes) -> void* {
        void* p = ws + off;
        off = (off + bytes + 255) & ~(size_t)255;
        return p;
    };
    int*   cnt    = (int*)carve(NEXP * 4);
    int*   offs   = (int*)carve((NEXP + 1) * 4);
    int*   cursor = (int*)carve(NEXP * 4);
    int*   work   = (int*)carve(64 * 4);
    int*   eids   = (int*)carve((size_t)T_TOK * 2 * 4);
    float* ews    = (float*)carve((size_t)T_TOK * 2 * 4);
    int*   tokid  = (int*)carve((size_t)(T_TOK * TOPK + 256) * 4);
    float* tokw   = (float*)carve((size_t)T_TOK * TOPK * 4);
    int*   pos    = (int*)carve((size_t)T_TOK * TOPK * 4);
    unsigned short* xb   = (unsigned short*)carve((size_t)T_TOK * HDIM * 2);
    unsigned short* w13b = (unsigned short*)carve((size_t)NEXP * 2 * IDIM * HDIM * 2);
    unsigned short* w2b  = (unsigned short*)carve((size_t)NEXP * HDIM * IDIM * 2);
    unsigned short* hbuf = (unsigned short*)carve((size_t)T_TOK * TOPK * IDIM * 2);
    unsigned short* pb   = (unsigned short*)carve((size_t)T_TOK * TOPK * HDIM * 2);

    hipFuncSetAttribute(reinterpret_cast<const void*>(gemm1_k),
                        hipFuncAttributeMaxDynamicSharedMemorySize, 2 * G1SLOT * 2);
    hipFuncSetAttribute(reinterpret_cast<const void*>(gemm2_k),
                        hipFuncAttributeMaxDynamicSharedMemorySize, 2 * G2SLOT * 2);

    init_k<<<1, 64, 0, stream>>>(cnt);
    router_k<<<T_TOK / 256, 256, 0, stream>>>(logits, cnt, eids, ews);
    offs_k<<<1, 1, 0, stream>>>(cnt, offs, cursor, work);
    scatter_k<<<T_TOK / 256, 256, 0, stream>>>(eids, ews, cursor, tokid, tokw, pos);

    cvt_all_k<<<4096, 256, 0, stream>>>(x, w13, w2, xb, w13b, w2b);

    gemm1_k<<<dim3(IDIM / 128, 40, 1), 512, 2 * G1SLOT * 2, stream>>>(xb, w13b, tokid, offs, work, hbuf);
    gemm2_k<<<dim3(HDIM / 128, 40, 1), 512, 2 * G2SLOT * 2, stream>>>(hbuf, w2b, offs, work, tokw, pb);

    combine2_k<<<(T_TOK * HDIM / 8) / 256, 256, 0, stream>>>(pb, pos, out);
}